// Round 3
// baseline (4984.963 us; speedup 1.0000x reference)
//
#include <hip/hip_runtime.h>
#include <math.h>

// B=32, R=16384, C=16, IC=16, OC=16, 3 routing iterations.
// x: (B,C,IC) fp32 [8192]; W: (R,C,OC,IC) fp32 [67108864 = 256 MB]; out: (B,C,OC) fp32.
//
// Algebra: logits are linear in v, so L3 = <u, v1+v2>; no L buffer needed.
// Un-normalized softmax (no max subtraction) is safe: |L| <~ 40, exp fits fp32.

#define RT 16384

__device__ __forceinline__ float rfl(float f) {   // force value into SGPR
    return __int_as_float(__builtin_amdgcn_readfirstlane(__float_as_int(f)));
}

// ---------------------------------------------------------------------------
// K1: wsum[c,o,i] = sum_r W[r,c,o,i].  W = 16,777,216 float4s.
// ---------------------------------------------------------------------------
__global__ __launch_bounds__(256) void k_wsum(const float4* __restrict__ W4,
                                              float* __restrict__ wsum) {
    int gid = blockIdx.x * 256 + threadIdx.x;      // [0, 262144)
    float4 acc = {0.f, 0.f, 0.f, 0.f};
    int idx = gid;
    #pragma unroll
    for (int it = 0; it < 64; ++it) {              // 16777216 / 262144 = 64
        float4 w = W4[idx];
        acc.x += w.x; acc.y += w.y; acc.z += w.z; acc.w += w.w;
        idx += 262144;
    }
    int cls = gid & 1023;                          // (c,o,i4) class
    atomicAdd(&wsum[cls * 4 + 0], acc.x);
    atomicAdd(&wsum[cls * 4 + 1], acc.y);
    atomicAdd(&wsum[cls * 4 + 2], acc.z);
    atomicAdd(&wsum[cls * 4 + 3], acc.w);
}

// ---------------------------------------------------------------------------
// K2: s1 = (1/R) * wsum . x ;  v1 = squash(s1)
// ---------------------------------------------------------------------------
__global__ __launch_bounds__(256) void k_v1(const float* __restrict__ wsum,
                                            const float* __restrict__ x,
                                            float* __restrict__ v1) {
    int t = blockIdx.x * 256 + threadIdx.x;        // 0..8191
    int o = t & 15, c = (t >> 4) & 15, b = t >> 8;
    const float* xb = x + (b * 16 + c) * 16;
    const float* wr = wsum + (c * 16 + o) * 16;
    float s = 0.f;
    #pragma unroll
    for (int i = 0; i < 16; ++i) s += wr[i] * xb[i];
    s *= (1.0f / 16384.0f);
    float ns = s * s;
    #pragma unroll
    for (int d = 1; d < 16; d <<= 1) ns += __shfl_xor(ns, d);
    v1[t] = s * (sqrtf(ns) / (1.0f + ns));
}

// ---------------------------------------------------------------------------
// K4: v = squash(E/Z); dst = v (+ addprev if given, producing v1+v2 table)
// ---------------------------------------------------------------------------
__global__ __launch_bounds__(256) void k_vout(const float* __restrict__ E,
                                              const float* __restrict__ Z,
                                              const float* __restrict__ addprev,
                                              float* __restrict__ dst) {
    int t = blockIdx.x * 256 + threadIdx.x;        // 0..8191
    float s = E[t] / Z[t >> 4];                    // t>>4 = b*16+c
    float ns = s * s;
    #pragma unroll
    for (int d = 1; d < 16; d <<= 1) ns += __shfl_xor(ns, d);
    float v = s * (sqrtf(ns) / (1.0f + ns));
    dst[t] = addprev ? (v + addprev[t]) : v;
}

// ---------------------------------------------------------------------------
// K3: fused routing pass.  Block 1024 = 16 waves; wave wv owns b in
// {2wv, 2wv+1}; lane = r within the 64-row chunk; 4 chunks/block.
// x,v tables readfirstlane'd into SGPRs (zero VGPR cost, scalar FMA srcs).
// W chunk register-prefetched (16 VGPRs) then ds_written with XOR swizzle.
// Grid (64, 16) covers (r, c).  ~110 VGPRs live -> no spill at the 128 cap.
// ---------------------------------------------------------------------------
__global__ __launch_bounds__(1024) void k_iter(const float* __restrict__ W,
                                               const float* __restrict__ x,
                                               const float* __restrict__ v,
                                               float* __restrict__ E,
                                               float* __restrict__ Z) {
    __shared__ float4 Wl[64 * 64];                 // 64 KB: 64 rows x 64 float4
    int c = blockIdx.y;
    int r0 = blockIdx.x * 256;
    int tid = threadIdx.x, wv = tid >> 6, lane = tid & 63;

    // wave-uniform x and v rows -> SGPRs (32 + 32)
    float xs[2][16], vs[2][16];
    #pragma unroll
    for (int bl = 0; bl < 2; ++bl) {
        int bc = (wv * 2 + bl) * 16 + c;
        #pragma unroll
        for (int i = 0; i < 16; ++i) {
            xs[bl][i] = rfl(x[bc * 16 + i]);
            vs[bl][i] = rfl(v[bc * 16 + i]);
        }
    }

    float accE[2][16];
    float accZ[2] = {0.f, 0.f};
    #pragma unroll
    for (int bl = 0; bl < 2; ++bl)
        #pragma unroll
        for (int o = 0; o < 16; ++o) accE[bl][o] = 0.f;

    // staging indices: thread t covers float4 linear idx t + k*1024 of the
    // 64-row x 64-float4 chunk; rl = idx>>6, j = idx&63 (j == lane)
    const int srl0 = tid >> 6;                     // rows srl0, srl0+16, +32, +48
    const int sj   = tid & 63;

    float4 pf[4];
    // prologue: prefetch chunk 0
    #pragma unroll
    for (int k = 0; k < 4; ++k) {
        int rl = srl0 + k * 16;
        pf[k] = *(const float4*)(W + ((size_t)(r0 + rl) * 16 + c) * 256 + sj * 4);
    }

    for (int chunk = 0; chunk < 4; ++chunk) {
        __syncthreads();                           // previous compute done
        #pragma unroll
        for (int k = 0; k < 4; ++k) {
            int rl = srl0 + k * 16;
            Wl[rl * 64 + (sj ^ rl)] = pf[k];
        }
        __syncthreads();                           // tile ready
        if (chunk < 3) {                           // prefetch next (overlaps compute)
            int rbase = r0 + (chunk + 1) * 64;
            #pragma unroll
            for (int k = 0; k < 4; ++k) {
                int rl = srl0 + k * 16;
                pf[k] = *(const float4*)(W + ((size_t)(rbase + rl) * 16 + c) * 256 + sj * 4);
            }
        }

        // compute: lane = row; u for 2 b's per wave
        float u[2][16];
        #pragma unroll
        for (int o = 0; o < 16; ++o) {
            float4 w0 = Wl[lane * 64 + ((o * 4 + 0) ^ lane)];
            float4 w1 = Wl[lane * 64 + ((o * 4 + 1) ^ lane)];
            float4 w2 = Wl[lane * 64 + ((o * 4 + 2) ^ lane)];
            float4 w3 = Wl[lane * 64 + ((o * 4 + 3) ^ lane)];
            #pragma unroll
            for (int bl = 0; bl < 2; ++bl) {
                u[bl][o] = w0.x * xs[bl][0]  + w0.y * xs[bl][1]
                         + w0.z * xs[bl][2]  + w0.w * xs[bl][3]
                         + w1.x * xs[bl][4]  + w1.y * xs[bl][5]
                         + w1.z * xs[bl][6]  + w1.w * xs[bl][7]
                         + w2.x * xs[bl][8]  + w2.y * xs[bl][9]
                         + w2.z * xs[bl][10] + w2.w * xs[bl][11]
                         + w3.x * xs[bl][12] + w3.y * xs[bl][13]
                         + w3.z * xs[bl][14] + w3.w * xs[bl][15];
            }
        }
        #pragma unroll
        for (int bl = 0; bl < 2; ++bl) {
            float Lv = 0.f;
            #pragma unroll
            for (int o = 0; o < 16; ++o) Lv += u[bl][o] * vs[bl][o];
            float e = __expf(Lv);
            accZ[bl] += e;
            #pragma unroll
            for (int o = 0; o < 16; ++o) accE[bl][o] += e * u[bl][o];
        }
    }

    // butterfly-reduce 32 accE + 2 accZ over the 64 lanes; 1 atomic per lane
    float va = 0.f, vz = 0.f;
    #pragma unroll
    for (int bl = 0; bl < 2; ++bl) {
        #pragma unroll
        for (int o = 0; o < 16; ++o) {
            float t = accE[bl][o];
            #pragma unroll
            for (int d = 1; d < 64; d <<= 1) t += __shfl_xor(t, d);
            if (lane == bl * 16 + o) va = t;
        }
        float t = accZ[bl];
        #pragma unroll
        for (int d = 1; d < 64; d <<= 1) t += __shfl_xor(t, d);
        if (lane == 32 + bl) vz = t;
    }
    if (lane < 32) {
        int b = wv * 2 + (lane >> 4);
        atomicAdd(&E[b * 256 + c * 16 + (lane & 15)], va);
    } else if (lane < 34) {
        int b = wv * 2 + (lane - 32);
        atomicAdd(&Z[b * 16 + c], vz);
    }
}

// ---------------------------------------------------------------------------
// launch
// ---------------------------------------------------------------------------
extern "C" void kernel_launch(void* const* d_in, const int* in_sizes, int n_in,
                              void* d_out, int out_size, void* d_ws, size_t ws_size,
                              hipStream_t stream) {
    const float* x = (const float*)d_in[0];        // 8192 floats
    const float* W = (const float*)d_in[1];        // 67108864 floats (256 MB)
    float* out = (float*)d_out;                    // 8192 floats
    float* ws = (float*)d_ws;

    float* wsum = ws + 0;          // 4096
    float* E2   = ws + 4096;       // 8192
    float* Z2   = ws + 12288;      // 512
    float* E3   = ws + 12800;      // 8192
    float* Z3   = ws + 20992;      // 512   (zeroed region ends at 21504)
    float* v1   = ws + 21504;      // 8192
    float* vsum = ws + 29696;      // 8192  (v1 + v2 for pass 3)

    hipMemsetAsync(ws, 0, 21504 * sizeof(float), stream);

    // iter 1: uniform softmax -> v1 from Wsum (W pass 1)
    k_wsum<<<1024, 256, 0, stream>>>((const float4*)W, wsum);
    k_v1<<<32, 256, 0, stream>>>(wsum, x, v1);

    // iter 2 fused: E2/Z2 from softmax(<u,v1>) (W pass 2)
    k_iter<<<dim3(64, 16), 1024, 0, stream>>>(W, x, v1, E2, Z2);
    k_vout<<<32, 256, 0, stream>>>(E2, Z2, v1, vsum);   // vsum = v1 + squash(E2/Z2)

    // iter 3 fused: E3/Z3 from softmax(<u,v1+v2>) (W pass 3)
    k_iter<<<dim3(64, 16), 1024, 0, stream>>>(W, x, vsum, E3, Z3);
    k_vout<<<32, 256, 0, stream>>>(E3, Z3, nullptr, out);
}